// Round 1
// baseline (732.131 us; speedup 1.0000x reference)
//
#include <hip/hip_runtime.h>
#include <math.h>

#define U_DIM 1024
#define B_DIM 32
#define S_DIM 2048
#define M_TOT (B_DIM * S_DIM)

typedef _Float16 half8 __attribute__((ext_vector_type(8)));
typedef _Float16 half4v __attribute__((ext_vector_type(4)));
typedef float f32x4 __attribute__((ext_vector_type(4)));

__device__ __forceinline__ void gload_lds16(const void* g, void* l) {
  __builtin_amdgcn_global_load_lds(
      (const __attribute__((address_space(1))) unsigned int*)g,
      (__attribute__((address_space(3))) unsigned int*)l,
      16, 0, 0);
}

// ---------------------------------------------------------------------------
// U_w (K x N, f32) -> UwT (N x K, fp16), LDS-tiled transpose
// ---------------------------------------------------------------------------
__global__ void conv_transpose_uw(const float* __restrict__ Uw,
                                  _Float16* __restrict__ UwT) {
  __shared__ float tile[32][33];
  const int bn = blockIdx.x, bk = blockIdx.y;
  const int c = threadIdx.x & 31, r0 = threadIdx.x >> 5;  // 32 cols x 8 rows
#pragma unroll
  for (int it = 0; it < 4; ++it) {
    int r = r0 + it * 8;
    tile[r][c] = Uw[(size_t)(bk * 32 + r) * U_DIM + bn * 32 + c];
  }
  __syncthreads();
#pragma unroll
  for (int it = 0; it < 4; ++it) {
    int r = r0 + it * 8;
    UwT[(size_t)(bn * 32 + r) * U_DIM + bk * 32 + c] = (_Float16)tile[c][r];
  }
}

// ---------------------------------------------------------------------------
// dec[b][h] = W_b[h] + sum_u s_prev[b][u] * W_w[u][h]   (f32, exact)
// grid: (4 h-chunks, 32 b), 256 threads
// ---------------------------------------------------------------------------
__launch_bounds__(256)
__global__ void decoder_kernel(const float* __restrict__ sp,
                               const float* __restrict__ Ww,
                               const float* __restrict__ Wb,
                               float* __restrict__ dec) {
  const int h = blockIdx.x * 256 + threadIdx.x;
  const int b = blockIdx.y;
  __shared__ float sprev[256];
  float acc = Wb[h];
  for (int u0 = 0; u0 < U_DIM; u0 += 256) {
    __syncthreads();
    sprev[threadIdx.x] = sp[b * U_DIM + u0 + threadIdx.x];
    __syncthreads();
#pragma unroll 8
    for (int uu = 0; uu < 256; ++uu)
      acc = fmaf(sprev[uu], Ww[(size_t)(u0 + uu) * U_DIM + h], acc);
  }
  dec[b * U_DIM + h] = acc;
}

// ---------------------------------------------------------------------------
// Fused: E = hs @ U_w ; t = tanh(E + Ub + dec) ; score += t @ V_w
// A (hs) reg-staged f32->fp16, B (UwT) via global_load_lds.
// 128x128 tile, BK=32, 4 waves (2x2), 16x16x32 f16 MFMA, 4x4 frags/wave.
// grid: 4096 blocks (512 M-tiles x 8 N-tiles), XCD-swizzled.
// ---------------------------------------------------------------------------
__launch_bounds__(256)
__global__ void gemm_score_kernel(const float* __restrict__ hs,
                                  const _Float16* __restrict__ UwT,
                                  const float* __restrict__ dec,
                                  const float* __restrict__ Ub,
                                  const float* __restrict__ Vw,
                                  float* __restrict__ score) {
  __shared__ _Float16 As[128 * 32];
  __shared__ _Float16 Bs[128 * 32];

  // XCD swizzle: 4096 blocks, 8 XCDs round-robin on bid&7.
  // XCD x owns M-tiles [64x, 64x+64), iterating all 8 N-tiles per M-tile,
  // so the A panel (256 KiB) is read once into that XCD's L2.
  const int bid = blockIdx.x;
  const int xcd = bid & 7;
  const int i = bid >> 3;
  const int tm = xcd * 64 + (i >> 3);
  const int tn = i & 7;
  const int m0 = tm * 128, n0 = tn * 128;

  const int t = threadIdx.x;
  const int lane = t & 63;
  const int wave = t >> 6;
  const int wr = wave >> 1, wc = wave & 1;

  f32x4 acc[4][4] = {};

  // A staging: 128x32 f32 tile = 1024 float4 chunks; 4 per thread.
  const float* aBase[4];
#pragma unroll
  for (int it = 0; it < 4; ++it) {
    int L = t + 256 * it;
    aBase[it] = hs + (size_t)(m0 + (L >> 3)) * U_DIM + ((L & 7) << 2);
  }
  // B staging: 128x32 fp16 tile = 512 x 16B; 2 per thread via global_load_lds.
  const _Float16* bBase0 = UwT + (size_t)(n0 + (t >> 2)) * U_DIM + ((t & 3) << 3);
  const _Float16* bBase1 = bBase0 + (size_t)64 * U_DIM;
  _Float16* lB0 = Bs + t * 8;
  _Float16* lB1 = Bs + t * 8 + 2048;
  half4v* lA = (half4v*)As;

  const int lr = lane & 15;
  const int lk = (lane >> 4) << 3;
  const int aoff = (wr * 64 + lr) * 32 + lk;
  const int boff = (wc * 64 + lr) * 32 + lk;

  for (int k0 = 0; k0 < U_DIM; k0 += 32) {
    gload_lds16(bBase0 + k0, lB0);
    gload_lds16(bBase1 + k0, lB1);
#pragma unroll
    for (int it = 0; it < 4; ++it) {
      float4 v = *(const float4*)(aBase[it] + k0);
      half4v h = {(_Float16)v.x, (_Float16)v.y, (_Float16)v.z, (_Float16)v.w};
      lA[t + 256 * it] = h;
    }
    __syncthreads();
    half8 af[4], bf[4];
#pragma unroll
    for (int q = 0; q < 4; ++q) af[q] = *(const half8*)&As[aoff + q * 16 * 32];
#pragma unroll
    for (int q = 0; q < 4; ++q) bf[q] = *(const half8*)&Bs[boff + q * 16 * 32];
#pragma unroll
    for (int a = 0; a < 4; ++a)
#pragma unroll
      for (int bq = 0; bq < 4; ++bq)
        acc[a][bq] = __builtin_amdgcn_mfma_f32_16x16x32_f16(af[a], bf[bq],
                                                            acc[a][bq], 0, 0, 0);
    __syncthreads();
  }

  // Epilogue: bias + tanh + V_w dot, row-reduce, atomic into score.
  // C/D layout: col = lane&15, row = (lane>>4)*4 + reg.
  const int b = m0 >> 11;  // /2048; BM=128 divides S so no tile spans batches
  float biasj[4], vwj[4];
#pragma unroll
  for (int j = 0; j < 4; ++j) {
    int n = n0 + wc * 64 + j * 16 + lr;
    biasj[j] = dec[b * U_DIM + n] + Ub[n];
    vwj[j] = Vw[n];
  }
  const int sbase = (m0 & (S_DIM - 1)) + wr * 64 + ((lane >> 4) << 2);
#pragma unroll
  for (int a = 0; a < 4; ++a) {
    float ps0 = 0.f, ps1 = 0.f, ps2 = 0.f, ps3 = 0.f;
#pragma unroll
    for (int j = 0; j < 4; ++j) {
      ps0 += tanhf(acc[a][j][0] + biasj[j]) * vwj[j];
      ps1 += tanhf(acc[a][j][1] + biasj[j]) * vwj[j];
      ps2 += tanhf(acc[a][j][2] + biasj[j]) * vwj[j];
      ps3 += tanhf(acc[a][j][3] + biasj[j]) * vwj[j];
    }
#pragma unroll
    for (int msk = 1; msk < 16; msk <<= 1) {
      ps0 += __shfl_xor(ps0, msk, 64);
      ps1 += __shfl_xor(ps1, msk, 64);
      ps2 += __shfl_xor(ps2, msk, 64);
      ps3 += __shfl_xor(ps3, msk, 64);
    }
    if (lr == 0) {
      float* spp = score + b * S_DIM + sbase + a * 16;
      atomicAdd(spp + 0, ps0);
      atomicAdd(spp + 1, ps1);
      atomicAdd(spp + 2, ps2);
      atomicAdd(spp + 3, ps3);
    }
  }
}

// ---------------------------------------------------------------------------
// alpha[b][s] = softmax over s of score[b][s]  (V_b shift is softmax-invariant)
// ---------------------------------------------------------------------------
__global__ void softmax_kernel(const float* __restrict__ score,
                               float* __restrict__ alpha) {
  const int b = blockIdx.x;
  const int t = threadIdx.x;  // 256
  float vals[8];
  float mx = -1e30f;
#pragma unroll
  for (int k = 0; k < 8; ++k) {
    vals[k] = score[b * S_DIM + t + k * 256];
    mx = fmaxf(mx, vals[k]);
  }
#pragma unroll
  for (int m = 1; m < 64; m <<= 1) mx = fmaxf(mx, __shfl_xor(mx, m, 64));
  __shared__ float smx[4], ssum[4];
  if ((t & 63) == 0) smx[t >> 6] = mx;
  __syncthreads();
  mx = fmaxf(fmaxf(smx[0], smx[1]), fmaxf(smx[2], smx[3]));
  float sum = 0.f;
#pragma unroll
  for (int k = 0; k < 8; ++k) {
    vals[k] = expf(vals[k] - mx);
    sum += vals[k];
  }
#pragma unroll
  for (int m = 1; m < 64; m <<= 1) sum += __shfl_xor(sum, m, 64);
  if ((t & 63) == 0) ssum[t >> 6] = sum;
  __syncthreads();
  sum = ssum[0] + ssum[1] + ssum[2] + ssum[3];
  const float inv = 1.0f / sum;
#pragma unroll
  for (int k = 0; k < 8; ++k)
    alpha[b * S_DIM + t + k * 256] = vals[k] * inv;
}

// ---------------------------------------------------------------------------
// ctx[b][h] = sum_s alpha[b][s] * hs[b][s][h]   (f32, memory-bound)
// grid: (16 s-chunks of 128, 32 b), 256 threads, float4 (4 h per thread)
// ---------------------------------------------------------------------------
__launch_bounds__(256)
__global__ void context_kernel(const float* __restrict__ hs,
                               const float* __restrict__ alpha,
                               float* __restrict__ ctx) {
  const int b = blockIdx.y;
  const int sc = blockIdx.x;
  const int t = threadIdx.x;
  __shared__ float al[128];
  if (t < 128) al[t] = alpha[b * S_DIM + sc * 128 + t];
  __syncthreads();
  const float4* hp =
      (const float4*)(hs + ((size_t)b * S_DIM + (size_t)sc * 128) * U_DIM) + t;
  float4 acc = {0.f, 0.f, 0.f, 0.f};
#pragma unroll 4
  for (int ss = 0; ss < 128; ++ss) {
    float a = al[ss];
    float4 h = hp[(size_t)ss * 256];
    acc.x = fmaf(a, h.x, acc.x);
    acc.y = fmaf(a, h.y, acc.y);
    acc.z = fmaf(a, h.z, acc.z);
    acc.w = fmaf(a, h.w, acc.w);
  }
  float* cp = ctx + b * U_DIM + t * 4;
  atomicAdd(cp + 0, acc.x);
  atomicAdd(cp + 1, acc.y);
  atomicAdd(cp + 2, acc.z);
  atomicAdd(cp + 3, acc.w);
}

// ---------------------------------------------------------------------------
extern "C" void kernel_launch(void* const* d_in, const int* in_sizes, int n_in,
                              void* d_out, int out_size, void* d_ws,
                              size_t ws_size, hipStream_t stream) {
  const float* s_prev = (const float*)d_in[0];
  const float* hs = (const float*)d_in[1];
  const float* Ww = (const float*)d_in[2];
  const float* Wb = (const float*)d_in[3];
  const float* Uw = (const float*)d_in[4];
  const float* Ub = (const float*)d_in[5];
  const float* Vw = (const float*)d_in[6];
  // d_in[7] = V_b: constant shift of scores -> softmax-invariant, unused.

  float* out = (float*)d_out;
  float* ctx = out;                     // (32, 1024)
  float* alpha = out + B_DIM * U_DIM;   // (32, 2048, 1)

  char* ws = (char*)d_ws;
  _Float16* UwT = (_Float16*)ws;                                 // 2 MiB
  float* dec = (float*)(ws + 2 * 1024 * 1024);                   // 128 KiB
  float* score = (float*)(ws + 2 * 1024 * 1024 + 128 * 1024);    // 256 KiB

  hipMemsetAsync(score, 0, (size_t)M_TOT * sizeof(float), stream);
  hipMemsetAsync(ctx, 0, (size_t)B_DIM * U_DIM * sizeof(float), stream);

  conv_transpose_uw<<<dim3(32, 32), 256, 0, stream>>>(Uw, UwT);
  decoder_kernel<<<dim3(4, B_DIM), 256, 0, stream>>>(s_prev, Ww, Wb, dec);
  gemm_score_kernel<<<4096, 256, 0, stream>>>(hs, UwT, dec, Ub, Vw, score);
  softmax_kernel<<<B_DIM, 256, 0, stream>>>(score, alpha);
  context_kernel<<<dim3(16, B_DIM), 256, 0, stream>>>(hs, alpha, ctx);
}

// Round 2
// 670.202 us; speedup vs baseline: 1.0924x; 1.0924x over previous
//
#include <hip/hip_runtime.h>
#include <math.h>

#define U_DIM 1024
#define B_DIM 32
#define S_DIM 2048
#define M_TOT (B_DIM * S_DIM)

typedef _Float16 half8 __attribute__((ext_vector_type(8)));
typedef _Float16 half4v __attribute__((ext_vector_type(4)));
typedef float f32x4 __attribute__((ext_vector_type(4)));

__device__ __forceinline__ void gload_lds16(const void* g, void* l) {
  __builtin_amdgcn_global_load_lds(
      (const __attribute__((address_space(1))) unsigned int*)g,
      (__attribute__((address_space(3))) unsigned int*)l,
      16, 0, 0);
}

// ---------------------------------------------------------------------------
// hs (f32) -> hsH (fp16), grid-stride, 8 elems/thread
// ---------------------------------------------------------------------------
__launch_bounds__(256)
__global__ void convert_hs(const float* __restrict__ in,
                           _Float16* __restrict__ out, size_t n8) {
  size_t i = (size_t)blockIdx.x * 256 + threadIdx.x;
  const size_t stride = (size_t)gridDim.x * 256;
  for (; i < n8; i += stride) {
    f32x4 a = ((const f32x4*)in)[2 * i];
    f32x4 b = ((const f32x4*)in)[2 * i + 1];
    half8 h = {(_Float16)a.x, (_Float16)a.y, (_Float16)a.z, (_Float16)a.w,
               (_Float16)b.x, (_Float16)b.y, (_Float16)b.z, (_Float16)b.w};
    ((half8*)out)[i] = h;
  }
}

// ---------------------------------------------------------------------------
// U_w (K x N, f32) -> UwT (N x K, fp16), LDS-tiled transpose
// ---------------------------------------------------------------------------
__global__ void conv_transpose_uw(const float* __restrict__ Uw,
                                  _Float16* __restrict__ UwT) {
  __shared__ float tile[32][33];
  const int bn = blockIdx.x, bk = blockIdx.y;
  const int c = threadIdx.x & 31, r0 = threadIdx.x >> 5;
#pragma unroll
  for (int it = 0; it < 4; ++it) {
    int r = r0 + it * 8;
    tile[r][c] = Uw[(size_t)(bk * 32 + r) * U_DIM + bn * 32 + c];
  }
  __syncthreads();
#pragma unroll
  for (int it = 0; it < 4; ++it) {
    int r = r0 + it * 8;
    UwT[(size_t)(bn * 32 + r) * U_DIM + bk * 32 + c] = (_Float16)tile[c][r];
  }
}

// ---------------------------------------------------------------------------
// dec[b][h] += sum_{u in chunk} sp[b][u]*Ww[u][h]  (+Wb once), atomics, f32
// grid: (8 u-chunks of 128, 32 b), 256 threads (4 h each, float4)
// ---------------------------------------------------------------------------
__launch_bounds__(256)
__global__ void decoder2(const float* __restrict__ sp,
                         const float* __restrict__ Ww,
                         const float* __restrict__ Wb,
                         float* __restrict__ dec) {
  const int b = blockIdx.y, u0 = blockIdx.x * 128, t = threadIdx.x;
  __shared__ float s[128];
  if (t < 128) s[t] = sp[b * U_DIM + u0 + t];
  __syncthreads();
  const f32x4* W4 = (const f32x4*)Ww + (size_t)u0 * 256 + t;
  f32x4 acc = {0.f, 0.f, 0.f, 0.f};
#pragma unroll 4
  for (int uu = 0; uu < 128; ++uu) {
    f32x4 w = W4[(size_t)uu * 256];
    float a = s[uu];
    acc.x = fmaf(a, w.x, acc.x);
    acc.y = fmaf(a, w.y, acc.y);
    acc.z = fmaf(a, w.z, acc.z);
    acc.w = fmaf(a, w.w, acc.w);
  }
  if (blockIdx.x == 0) {
    const f32x4 wb = ((const f32x4*)Wb)[t];
    acc.x += wb.x; acc.y += wb.y; acc.z += wb.z; acc.w += wb.w;
  }
  float* dp = dec + b * U_DIM + t * 4;
  atomicAdd(dp + 0, acc.x);
  atomicAdd(dp + 1, acc.y);
  atomicAdd(dp + 2, acc.z);
  atomicAdd(dp + 3, acc.w);
}

// ---------------------------------------------------------------------------
// Shared epilogue: bias + tanh + V_w dot, row-reduce, atomic into score.
// ---------------------------------------------------------------------------
__device__ __forceinline__ void score_epilogue(
    f32x4 (&acc)[4][4], int m0, int n0, int wr, int wc, int lane,
    const float* __restrict__ dec, const float* __restrict__ Ub,
    const float* __restrict__ Vw, float* __restrict__ score) {
  const int lr = lane & 15;
  const int b = m0 >> 11;
  float biasj[4], vwj[4];
#pragma unroll
  for (int j = 0; j < 4; ++j) {
    int n = n0 + wc * 64 + j * 16 + lr;
    biasj[j] = dec[b * U_DIM + n] + Ub[n];
    vwj[j] = Vw[n];
  }
  const int sbase = (m0 & (S_DIM - 1)) + wr * 64 + ((lane >> 4) << 2);
#pragma unroll
  for (int a = 0; a < 4; ++a) {
    float ps0 = 0.f, ps1 = 0.f, ps2 = 0.f, ps3 = 0.f;
#pragma unroll
    for (int j = 0; j < 4; ++j) {
      ps0 += tanhf(acc[a][j][0] + biasj[j]) * vwj[j];
      ps1 += tanhf(acc[a][j][1] + biasj[j]) * vwj[j];
      ps2 += tanhf(acc[a][j][2] + biasj[j]) * vwj[j];
      ps3 += tanhf(acc[a][j][3] + biasj[j]) * vwj[j];
    }
#pragma unroll
    for (int msk = 1; msk < 16; msk <<= 1) {
      ps0 += __shfl_xor(ps0, msk, 64);
      ps1 += __shfl_xor(ps1, msk, 64);
      ps2 += __shfl_xor(ps2, msk, 64);
      ps3 += __shfl_xor(ps3, msk, 64);
    }
    if (lr == 0) {
      float* spp = score + b * S_DIM + sbase + a * 16;
      atomicAdd(spp + 0, ps0);
      atomicAdd(spp + 1, ps1);
      atomicAdd(spp + 2, ps2);
      atomicAdd(spp + 3, ps3);
    }
  }
}

// ---------------------------------------------------------------------------
// FAST GEMM: A (fp16 hsH) and B (fp16 UwT) both via global_load_lds.
// 128x128 tile, BK=32, 4 waves (2x2), 16x16x32 f16 MFMA. m97 structure.
// ---------------------------------------------------------------------------
__launch_bounds__(256)
__global__ void gemm_score_h(const _Float16* __restrict__ Ah,
                             const _Float16* __restrict__ UwT,
                             const float* __restrict__ dec,
                             const float* __restrict__ Ub,
                             const float* __restrict__ Vw,
                             float* __restrict__ score) {
  __shared__ _Float16 As[128 * 32];
  __shared__ _Float16 Bs[128 * 32];

  const int bid = blockIdx.x;
  const int xcd = bid & 7;
  const int i = bid >> 3;
  const int tm = xcd * 64 + (i >> 3);
  const int tn = i & 7;
  const int m0 = tm * 128, n0 = tn * 128;

  const int t = threadIdx.x;
  const int lane = t & 63;
  const int wave = t >> 6;
  const int wr = wave >> 1, wc = wave & 1;

  f32x4 acc[4][4] = {};

  // 16B chunks: chunk c -> row c>>2, fp16-col (c&3)*8; LDS byte c*16 (linear).
  const _Float16* aSrc0 = Ah + (size_t)(m0 + (t >> 2)) * U_DIM + ((t & 3) << 3);
  const _Float16* aSrc1 = aSrc0 + (size_t)64 * U_DIM;
  const _Float16* bSrc0 = UwT + (size_t)(n0 + (t >> 2)) * U_DIM + ((t & 3) << 3);
  const _Float16* bSrc1 = bSrc0 + (size_t)64 * U_DIM;
  _Float16* lA0 = As + t * 8;
  _Float16* lA1 = As + t * 8 + 2048;
  _Float16* lB0 = Bs + t * 8;
  _Float16* lB1 = Bs + t * 8 + 2048;

  const int lr = lane & 15;
  const int lk = (lane >> 4) << 3;
  const int aoff = (wr * 64 + lr) * 32 + lk;
  const int boff = (wc * 64 + lr) * 32 + lk;

  for (int k0 = 0; k0 < U_DIM; k0 += 32) {
    gload_lds16(aSrc0 + k0, lA0);
    gload_lds16(aSrc1 + k0, lA1);
    gload_lds16(bSrc0 + k0, lB0);
    gload_lds16(bSrc1 + k0, lB1);
    __syncthreads();
    half8 af[4], bf[4];
#pragma unroll
    for (int q = 0; q < 4; ++q) af[q] = *(const half8*)&As[aoff + q * 16 * 32];
#pragma unroll
    for (int q = 0; q < 4; ++q) bf[q] = *(const half8*)&Bs[boff + q * 16 * 32];
#pragma unroll
    for (int a = 0; a < 4; ++a)
#pragma unroll
      for (int bq = 0; bq < 4; ++bq)
        acc[a][bq] = __builtin_amdgcn_mfma_f32_16x16x32_f16(af[a], bf[bq],
                                                            acc[a][bq], 0, 0, 0);
    __syncthreads();
  }
  score_epilogue(acc, m0, n0, wr, wc, lane, dec, Ub, Vw, score);
}

// ---------------------------------------------------------------------------
// FALLBACK GEMM (ws too small): A reg-staged f32->fp16 (round-1 kernel).
// ---------------------------------------------------------------------------
__launch_bounds__(256)
__global__ void gemm_score_f32(const float* __restrict__ hs,
                               const _Float16* __restrict__ UwT,
                               const float* __restrict__ dec,
                               const float* __restrict__ Ub,
                               const float* __restrict__ Vw,
                               float* __restrict__ score) {
  __shared__ _Float16 As[128 * 32];
  __shared__ _Float16 Bs[128 * 32];

  const int bid = blockIdx.x;
  const int xcd = bid & 7;
  const int i = bid >> 3;
  const int tm = xcd * 64 + (i >> 3);
  const int tn = i & 7;
  const int m0 = tm * 128, n0 = tn * 128;

  const int t = threadIdx.x;
  const int lane = t & 63;
  const int wave = t >> 6;
  const int wr = wave >> 1, wc = wave & 1;

  f32x4 acc[4][4] = {};

  const float* aBase[4];
#pragma unroll
  for (int it = 0; it < 4; ++it) {
    int L = t + 256 * it;
    aBase[it] = hs + (size_t)(m0 + (L >> 3)) * U_DIM + ((L & 7) << 2);
  }
  const _Float16* bBase0 = UwT + (size_t)(n0 + (t >> 2)) * U_DIM + ((t & 3) << 3);
  const _Float16* bBase1 = bBase0 + (size_t)64 * U_DIM;
  _Float16* lB0 = Bs + t * 8;
  _Float16* lB1 = Bs + t * 8 + 2048;
  half4v* lA = (half4v*)As;

  const int lr = lane & 15;
  const int lk = (lane >> 4) << 3;
  const int aoff = (wr * 64 + lr) * 32 + lk;
  const int boff = (wc * 64 + lr) * 32 + lk;

  for (int k0 = 0; k0 < U_DIM; k0 += 32) {
    gload_lds16(bBase0 + k0, lB0);
    gload_lds16(bBase1 + k0, lB1);
#pragma unroll
    for (int it = 0; it < 4; ++it) {
      float4 v = *(const float4*)(aBase[it] + k0);
      half4v h = {(_Float16)v.x, (_Float16)v.y, (_Float16)v.z, (_Float16)v.w};
      lA[t + 256 * it] = h;
    }
    __syncthreads();
    half8 af[4], bf[4];
#pragma unroll
    for (int q = 0; q < 4; ++q) af[q] = *(const half8*)&As[aoff + q * 16 * 32];
#pragma unroll
    for (int q = 0; q < 4; ++q) bf[q] = *(const half8*)&Bs[boff + q * 16 * 32];
#pragma unroll
    for (int a = 0; a < 4; ++a)
#pragma unroll
      for (int bq = 0; bq < 4; ++bq)
        acc[a][bq] = __builtin_amdgcn_mfma_f32_16x16x32_f16(af[a], bf[bq],
                                                            acc[a][bq], 0, 0, 0);
    __syncthreads();
  }
  score_epilogue(acc, m0, n0, wr, wc, lane, dec, Ub, Vw, score);
}

// ---------------------------------------------------------------------------
// alpha = softmax(score) over S
// ---------------------------------------------------------------------------
__global__ void softmax_kernel(const float* __restrict__ score,
                               float* __restrict__ alpha) {
  const int b = blockIdx.x;
  const int t = threadIdx.x;
  float vals[8];
  float mx = -1e30f;
#pragma unroll
  for (int k = 0; k < 8; ++k) {
    vals[k] = score[b * S_DIM + t + k * 256];
    mx = fmaxf(mx, vals[k]);
  }
#pragma unroll
  for (int m = 1; m < 64; m <<= 1) mx = fmaxf(mx, __shfl_xor(mx, m, 64));
  __shared__ float smx[4], ssum[4];
  if ((t & 63) == 0) smx[t >> 6] = mx;
  __syncthreads();
  mx = fmaxf(fmaxf(smx[0], smx[1]), fmaxf(smx[2], smx[3]));
  float sum = 0.f;
#pragma unroll
  for (int k = 0; k < 8; ++k) {
    vals[k] = expf(vals[k] - mx);
    sum += vals[k];
  }
#pragma unroll
  for (int m = 1; m < 64; m <<= 1) sum += __shfl_xor(sum, m, 64);
  if ((t & 63) == 0) ssum[t >> 6] = sum;
  __syncthreads();
  sum = ssum[0] + ssum[1] + ssum[2] + ssum[3];
  const float inv = 1.0f / sum;
#pragma unroll
  for (int k = 0; k < 8; ++k)
    alpha[b * S_DIM + t + k * 256] = vals[k] * inv;
}

// ---------------------------------------------------------------------------
// ctx[b][h] = sum_s alpha[b][s]*hsH[b][s][h]  — fp16 input version
// grid (16 s-chunks of 128, 32 b), 256 thr: t&127 -> half8 chunk, t>>7 -> parity
// ---------------------------------------------------------------------------
__launch_bounds__(256)
__global__ void context_h(const _Float16* __restrict__ hsH,
                          const float* __restrict__ alpha,
                          float* __restrict__ ctx) {
  const int b = blockIdx.y, sc = blockIdx.x, t = threadIdx.x;
  __shared__ float al[128];
  __shared__ float red[128][8];
  if (t < 128) al[t] = alpha[b * S_DIM + sc * 128 + t];
  __syncthreads();
  const int hc = t & 127;
  const int p = t >> 7;
  const half8* hp =
      (const half8*)(hsH + ((size_t)b * S_DIM + sc * 128 + p) * U_DIM) + hc;
  float a8[8] = {};
#pragma unroll 4
  for (int i = 0; i < 64; ++i) {
    float a = al[2 * i + p];
    half8 h = hp[(size_t)i * 256];
#pragma unroll
    for (int j = 0; j < 8; ++j) a8[j] = fmaf(a, (float)h[j], a8[j]);
  }
  if (p == 1) {
#pragma unroll
    for (int j = 0; j < 8; ++j) red[hc][j] = a8[j];
  }
  __syncthreads();
  if (p == 0) {
    float* cp = ctx + b * U_DIM + hc * 8;
#pragma unroll
    for (int j = 0; j < 8; ++j) atomicAdd(cp + j, a8[j] + red[hc][j]);
  }
}

// f32 fallback context (round-1 kernel)
__launch_bounds__(256)
__global__ void context_f32(const float* __restrict__ hs,
                            const float* __restrict__ alpha,
                            float* __restrict__ ctx) {
  const int b = blockIdx.y;
  const int sc = blockIdx.x;
  const int t = threadIdx.x;
  __shared__ float al[128];
  if (t < 128) al[t] = alpha[b * S_DIM + sc * 128 + t];
  __syncthreads();
  const float4* hp =
      (const float4*)(hs + ((size_t)b * S_DIM + (size_t)sc * 128) * U_DIM) + t;
  float4 acc = {0.f, 0.f, 0.f, 0.f};
#pragma unroll 4
  for (int ss = 0; ss < 128; ++ss) {
    float a = al[ss];
    float4 h = hp[(size_t)ss * 256];
    acc.x = fmaf(a, h.x, acc.x);
    acc.y = fmaf(a, h.y, acc.y);
    acc.z = fmaf(a, h.z, acc.z);
    acc.w = fmaf(a, h.w, acc.w);
  }
  float* cp = ctx + b * U_DIM + t * 4;
  atomicAdd(cp + 0, acc.x);
  atomicAdd(cp + 1, acc.y);
  atomicAdd(cp + 2, acc.z);
  atomicAdd(cp + 3, acc.w);
}

// ---------------------------------------------------------------------------
extern "C" void kernel_launch(void* const* d_in, const int* in_sizes, int n_in,
                              void* d_out, int out_size, void* d_ws,
                              size_t ws_size, hipStream_t stream) {
  const float* s_prev = (const float*)d_in[0];
  const float* hs = (const float*)d_in[1];
  const float* Ww = (const float*)d_in[2];
  const float* Wb = (const float*)d_in[3];
  const float* Uw = (const float*)d_in[4];
  const float* Ub = (const float*)d_in[5];
  const float* Vw = (const float*)d_in[6];
  // d_in[7] = V_b: softmax-invariant constant shift, unused.

  float* out = (float*)d_out;
  float* ctx = out;
  float* alpha = out + B_DIM * U_DIM;

  const size_t HSH_BYTES = (size_t)M_TOT * U_DIM * sizeof(_Float16);  // 128 MiB
  const size_t UWT_BYTES = (size_t)U_DIM * U_DIM * sizeof(_Float16);  // 2 MiB
  const size_t DEC_BYTES = (size_t)B_DIM * U_DIM * sizeof(float);     // 128 KiB
  const size_t SCORE_BYTES = (size_t)M_TOT * sizeof(float);           // 256 KiB
  const bool fast = ws_size >= HSH_BYTES + UWT_BYTES + DEC_BYTES + SCORE_BYTES;

  char* ws = (char*)d_ws;
  _Float16* hsH = (_Float16*)ws;
  char* base = fast ? ws + HSH_BYTES : ws;
  _Float16* UwT = (_Float16*)base;
  float* dec = (float*)(base + UWT_BYTES);
  float* score = (float*)(base + UWT_BYTES + DEC_BYTES);

  hipMemsetAsync(dec, 0, DEC_BYTES, stream);
  hipMemsetAsync(score, 0, SCORE_BYTES, stream);
  hipMemsetAsync(ctx, 0, (size_t)B_DIM * U_DIM * sizeof(float), stream);

  conv_transpose_uw<<<dim3(32, 32), 256, 0, stream>>>(Uw, UwT);
  decoder2<<<dim3(8, B_DIM), 256, 0, stream>>>(s_prev, Ww, Wb, dec);

  if (fast) {
    convert_hs<<<2048, 256, 0, stream>>>(hs, hsH, (size_t)M_TOT * U_DIM / 8);
    gemm_score_h<<<4096, 256, 0, stream>>>(hsH, UwT, dec, Ub, Vw, score);
  } else {
    gemm_score_f32<<<4096, 256, 0, stream>>>(hs, UwT, dec, Ub, Vw, score);
  }

  softmax_kernel<<<B_DIM, 256, 0, stream>>>(score, alpha);

  if (fast) {
    context_h<<<dim3(16, B_DIM), 256, 0, stream>>>(hsH, alpha, ctx);
  } else {
    context_f32<<<dim3(16, B_DIM), 256, 0, stream>>>(hs, alpha, ctx);
  }
}

// Round 3
// 642.605 us; speedup vs baseline: 1.1393x; 1.0429x over previous
//
#include <hip/hip_runtime.h>
#include <math.h>

#define U_DIM 1024
#define B_DIM 32
#define S_DIM 2048
#define M_TOT (B_DIM * S_DIM)

typedef _Float16 half8 __attribute__((ext_vector_type(8)));
typedef float f32x4 __attribute__((ext_vector_type(4)));

__device__ __forceinline__ void gload_lds16(const void* g, void* l) {
  __builtin_amdgcn_global_load_lds(
      (const __attribute__((address_space(1))) unsigned int*)g,
      (__attribute__((address_space(3))) unsigned int*)l,
      16, 0, 0);
}

// tanh via e^{2x}: tanh(x) = 1 - 2/(e^{2x}+1); exp2f -> v_exp_f32, rcp HW approx
__device__ __forceinline__ float tanh_fast(float x) {
  float e = exp2f(x * 2.88539008177792681f);  // e^{2x}
  return 1.0f - 2.0f * __builtin_amdgcn_rcpf(e + 1.0f);
}

// ---------------------------------------------------------------------------
// hs (f32) -> hsH (fp16), grid-stride
// ---------------------------------------------------------------------------
__launch_bounds__(256)
__global__ void convert_hs(const float* __restrict__ in,
                           _Float16* __restrict__ out, size_t n8) {
  size_t i = (size_t)blockIdx.x * 256 + threadIdx.x;
  const size_t stride = (size_t)gridDim.x * 256;
  for (; i < n8; i += stride) {
    f32x4 a = ((const f32x4*)in)[2 * i];
    f32x4 b = ((const f32x4*)in)[2 * i + 1];
    half8 h = {(_Float16)a.x, (_Float16)a.y, (_Float16)a.z, (_Float16)a.w,
               (_Float16)b.x, (_Float16)b.y, (_Float16)b.z, (_Float16)b.w};
    ((half8*)out)[i] = h;
  }
}

// ---------------------------------------------------------------------------
// U_w (K x N, f32) -> UwT (N x K, fp16), LDS-tiled transpose
// ---------------------------------------------------------------------------
__global__ void conv_transpose_uw(const float* __restrict__ Uw,
                                  _Float16* __restrict__ UwT) {
  __shared__ float tile[32][33];
  const int bn = blockIdx.x, bk = blockIdx.y;
  const int c = threadIdx.x & 31, r0 = threadIdx.x >> 5;
#pragma unroll
  for (int it = 0; it < 4; ++it) {
    int r = r0 + it * 8;
    tile[r][c] = Uw[(size_t)(bk * 32 + r) * U_DIM + bn * 32 + c];
  }
  __syncthreads();
#pragma unroll
  for (int it = 0; it < 4; ++it) {
    int r = r0 + it * 8;
    UwT[(size_t)(bn * 32 + r) * U_DIM + bk * 32 + c] = (_Float16)tile[c][r];
  }
}

// ---------------------------------------------------------------------------
// dec[b][h] += partial GEMV of s_prev @ W_w (+Wb), f32
// ---------------------------------------------------------------------------
__launch_bounds__(256)
__global__ void decoder2(const float* __restrict__ sp,
                         const float* __restrict__ Ww,
                         const float* __restrict__ Wb,
                         float* __restrict__ dec) {
  const int b = blockIdx.y, u0 = blockIdx.x * 128, t = threadIdx.x;
  __shared__ float s[128];
  if (t < 128) s[t] = sp[b * U_DIM + u0 + t];
  __syncthreads();
  const f32x4* W4 = (const f32x4*)Ww + (size_t)u0 * 256 + t;
  f32x4 acc = {0.f, 0.f, 0.f, 0.f};
#pragma unroll 4
  for (int uu = 0; uu < 128; ++uu) {
    f32x4 w = W4[(size_t)uu * 256];
    float a = s[uu];
    acc.x = fmaf(a, w.x, acc.x);
    acc.y = fmaf(a, w.y, acc.y);
    acc.z = fmaf(a, w.z, acc.z);
    acc.w = fmaf(a, w.w, acc.w);
  }
  if (blockIdx.x == 0) {
    const f32x4 wb = ((const f32x4*)Wb)[t];
    acc.x += wb.x; acc.y += wb.y; acc.z += wb.z; acc.w += wb.w;
  }
  float* dp = dec + b * U_DIM + t * 4;
  atomicAdd(dp + 0, acc.x);
  atomicAdd(dp + 1, acc.y);
  atomicAdd(dp + 2, acc.z);
  atomicAdd(dp + 3, acc.w);
}

// ---------------------------------------------------------------------------
// 8-phase 256x256 GEMM + fused tanh/Vw epilogue.
// BK=64, 8 waves (2Mx4N), per-wave 128x64, 16x16x32 f16 MFMA.
// LDS: 2 x [256][64] fp16 per operand = 128 KiB, XOR-16B-slot swizzle.
// Counted vmcnt(8) at tile boundaries (1 K-tile always in flight).
// ---------------------------------------------------------------------------
__launch_bounds__(512, 2)
__global__ void gemm_score_8p(const _Float16* __restrict__ Ah,
                              const _Float16* __restrict__ UwT,
                              const float* __restrict__ dec,
                              const float* __restrict__ Ub,
                              const float* __restrict__ Vw,
                              float* __restrict__ score) {
  __shared__ _Float16 As[2][256 * 64];  // 64 KiB
  __shared__ _Float16 Bs[2][256 * 64];  // 64 KiB

  // XCD-bijective swizzle: 1024 blocks = 8 XCD x 128. tn inner (4 N-tiles
  // share an A panel within one XCD's L2).
  const int bid = blockIdx.x;
  const int lin = (bid & 7) * 128 + (bid >> 3);
  const int tm = lin >> 2, tn = lin & 3;
  const int m0 = tm * 256, n0 = tn * 256;

  const int t = threadIdx.x;
  const int lane = t & 63;
  const int w = t >> 6;
  const int wm = w >> 2, wn = w & 3;
  const int g = lane >> 4, lr = lane & 15;

  // Staging: 2048 16B-chunks per operand per K-tile; 4 each per thread.
  // Physical chunk c -> row c>>3, slot c&7; holds logical slot (c&7)^(row&7).
  const _Float16* aSrc[4];
  const _Float16* bSrc[4];
  int dstOff[4];
#pragma unroll
  for (int L = 0; L < 4; ++L) {
    int c = t + 512 * L;
    int row = c >> 3;
    int ls = (c & 7) ^ (row & 7);
    aSrc[L] = Ah + (size_t)(m0 + row) * U_DIM + ls * 8;
    bSrc[L] = UwT + (size_t)(n0 + row) * U_DIM + ls * 8;
    dstOff[L] = c * 8;
  }

  f32x4 acc[8][4] = {};

  // fragment read offsets (fp16 units). phys slot = (kk*4+g) ^ (lr&7)
  const int aro = (wm * 128 + lr) * 64;
  const int bro = (wn * 64 + lr) * 64;
  int slot[2];
#pragma unroll
  for (int kk = 0; kk < 2; ++kk) slot[kk] = (((kk << 2) | g) ^ (lr & 7)) * 8;

  // prologue: stage K-tile 0 into buffer 0
#pragma unroll
  for (int L = 0; L < 4; ++L) {
    gload_lds16(aSrc[L], &As[0][dstOff[L]]);
    gload_lds16(bSrc[L], &Bs[0][dstOff[L]]);
  }

  const int NT = U_DIM / 64;  // 16
  for (int kt = 0; kt < NT; ++kt) {
    const int P = kt & 1;
    if (kt + 1 < NT) {
      const int koff = (kt + 1) * 64;
#pragma unroll
      for (int L = 0; L < 4; ++L) {
        gload_lds16(aSrc[L] + koff, &As[P ^ 1][dstOff[L]]);
        gload_lds16(bSrc[L] + koff, &Bs[P ^ 1][dstOff[L]]);
      }
      // oldest 8 = this tile's loads drain; next tile's 8 stay in flight
      asm volatile("s_waitcnt vmcnt(8)" ::: "memory");
    } else {
      asm volatile("s_waitcnt vmcnt(0)" ::: "memory");
    }
    __builtin_amdgcn_s_barrier();
    asm volatile("" ::: "memory");

    const _Float16* A_ = As[P];
    const _Float16* B_ = Bs[P];
    half8 af[4][2], bf[2][2];

    // ---- phase 0: mh=0, nh=0 (read A-half0 + B-quarter0) ----
#pragma unroll
    for (int i = 0; i < 4; ++i)
#pragma unroll
      for (int kk = 0; kk < 2; ++kk)
        af[i][kk] = *(const half8*)&A_[aro + i * 1024 + slot[kk]];
#pragma unroll
    for (int j = 0; j < 2; ++j)
#pragma unroll
      for (int kk = 0; kk < 2; ++kk)
        bf[j][kk] = *(const half8*)&B_[bro + j * 1024 + slot[kk]];
    __builtin_amdgcn_s_setprio(1);
#pragma unroll
    for (int i = 0; i < 4; ++i)
#pragma unroll
      for (int j = 0; j < 2; ++j)
#pragma unroll
        for (int kk = 0; kk < 2; ++kk)
          acc[i][j] = __builtin_amdgcn_mfma_f32_16x16x32_f16(
              af[i][kk], bf[j][kk], acc[i][j], 0, 0, 0);
    __builtin_amdgcn_s_setprio(0);
    __builtin_amdgcn_s_barrier();
    asm volatile("" ::: "memory");

    // ---- phase 1: mh=0, nh=1 (read B-quarter1, reuse A) ----
#pragma unroll
    for (int j = 0; j < 2; ++j)
#pragma unroll
      for (int kk = 0; kk < 2; ++kk)
        bf[j][kk] = *(const half8*)&B_[bro + (2 + j) * 1024 + slot[kk]];
    __builtin_amdgcn_s_setprio(1);
#pragma unroll
    for (int i = 0; i < 4; ++i)
#pragma unroll
      for (int j = 0; j < 2; ++j)
#pragma unroll
        for (int kk = 0; kk < 2; ++kk)
          acc[i][2 + j] = __builtin_amdgcn_mfma_f32_16x16x32_f16(
              af[i][kk], bf[j][kk], acc[i][2 + j], 0, 0, 0);
    __builtin_amdgcn_s_setprio(0);
    __builtin_amdgcn_s_barrier();
    asm volatile("" ::: "memory");

    // ---- phase 2: mh=1, nh=1 (read A-half1, reuse B) ----
#pragma unroll
    for (int i = 0; i < 4; ++i)
#pragma unroll
      for (int kk = 0; kk < 2; ++kk)
        af[i][kk] = *(const half8*)&A_[aro + 4096 + i * 1024 + slot[kk]];
    __builtin_amdgcn_s_setprio(1);
#pragma unroll
    for (int i = 0; i < 4; ++i)
#pragma unroll
      for (int j = 0; j < 2; ++j)
#pragma unroll
        for (int kk = 0; kk < 2; ++kk)
          acc[4 + i][2 + j] = __builtin_amdgcn_mfma_f32_16x16x32_f16(
              af[i][kk], bf[j][kk], acc[4 + i][2 + j], 0, 0, 0);
    __builtin_amdgcn_s_setprio(0);
    __builtin_amdgcn_s_barrier();
    asm volatile("" ::: "memory");

    // ---- phase 3: mh=1, nh=0 (re-read B-quarter0, reuse A) ----
#pragma unroll
    for (int j = 0; j < 2; ++j)
#pragma unroll
      for (int kk = 0; kk < 2; ++kk)
        bf[j][kk] = *(const half8*)&B_[bro + j * 1024 + slot[kk]];
    __builtin_amdgcn_s_setprio(1);
#pragma unroll
    for (int i = 0; i < 4; ++i)
#pragma unroll
      for (int j = 0; j < 2; ++j)
#pragma unroll
        for (int kk = 0; kk < 2; ++kk)
          acc[4 + i][j] = __builtin_amdgcn_mfma_f32_16x16x32_f16(
              af[i][kk], bf[j][kk], acc[4 + i][j], 0, 0, 0);
    __builtin_amdgcn_s_setprio(0);
    __builtin_amdgcn_s_barrier();  // end-of-tile: protects buf[P] from next staging
    asm volatile("" ::: "memory");
  }

  __syncthreads();

  // Epilogue: tanh + Vw dot; LDS reduction over the 256-col block slice.
  float* red = (float*)&As[0][0];  // [256][64] f32 = 64 KiB
  const int b = m0 >> 11;
  float biasv[4], vwv[4];
#pragma unroll
  for (int j = 0; j < 4; ++j) {
    int n = n0 + wn * 64 + j * 16 + lr;
    biasv[j] = dec[b * U_DIM + n] + Ub[n];
    vwv[j] = Vw[n];
  }
#pragma unroll
  for (int mi = 0; mi < 8; ++mi)
#pragma unroll
    for (int r = 0; r < 4; ++r) {
      float s = 0.f;
#pragma unroll
      for (int j = 0; j < 4; ++j)
        s += tanh_fast(acc[mi][j][r] + biasv[j]) * vwv[j];
      int rl = wm * 128 + mi * 16 + g * 4 + r;
      red[rl * 64 + wn * 16 + lr] = s;
    }
  __syncthreads();
  if (t < 256) {
    float sum = 0.f;
    const f32x4* rp = (const f32x4*)&red[t * 64];
#pragma unroll
    for (int k = 0; k < 16; ++k) {  // rotated to avoid bank aliasing
      f32x4 v = rp[(k + t) & 15];
      sum += v.x + v.y + v.z + v.w;
    }
    atomicAdd(score + b * S_DIM + (m0 & (S_DIM - 1)) + t, sum);
  }
}

// ---------------------------------------------------------------------------
// alpha = softmax(score) over S (V_b shift is softmax-invariant)
// ---------------------------------------------------------------------------
__global__ void softmax_kernel(const float* __restrict__ score,
                               float* __restrict__ alpha) {
  const int b = blockIdx.x;
  const int t = threadIdx.x;
  float vals[8];
  float mx = -1e30f;
#pragma unroll
  for (int k = 0; k < 8; ++k) {
    vals[k] = score[b * S_DIM + t + k * 256];
    mx = fmaxf(mx, vals[k]);
  }
#pragma unroll
  for (int m = 1; m < 64; m <<= 1) mx = fmaxf(mx, __shfl_xor(mx, m, 64));
  __shared__ float smx[4], ssum[4];
  if ((t & 63) == 0) smx[t >> 6] = mx;
  __syncthreads();
  mx = fmaxf(fmaxf(smx[0], smx[1]), fmaxf(smx[2], smx[3]));
  float sum = 0.f;
#pragma unroll
  for (int k = 0; k < 8; ++k) {
    vals[k] = expf(vals[k] - mx);
    sum += vals[k];
  }
#pragma unroll
  for (int m = 1; m < 64; m <<= 1) sum += __shfl_xor(sum, m, 64);
  if ((t & 63) == 0) ssum[t >> 6] = sum;
  __syncthreads();
  sum = ssum[0] + ssum[1] + ssum[2] + ssum[3];
  const float inv = 1.0f / sum;
#pragma unroll
  for (int k = 0; k < 8; ++k)
    alpha[b * S_DIM + t + k * 256] = vals[k] * inv;
}

// ---------------------------------------------------------------------------
// ctx[b][h] = sum_s alpha[b][s]*hsH[b][s][h]; grid (32 s-chunks, 32 b)
// ---------------------------------------------------------------------------
__launch_bounds__(256)
__global__ void context_h(const _Float16* __restrict__ hsH,
                          const float* __restrict__ alpha,
                          float* __restrict__ ctx) {
  const int b = blockIdx.y, sc = blockIdx.x, t = threadIdx.x;
  __shared__ float al[64];
  __shared__ float red[128][8];
  if (t < 64) al[t] = alpha[b * S_DIM + sc * 64 + t];
  __syncthreads();
  const int hc = t & 127;
  const int p = t >> 7;
  const half8* hp =
      (const half8*)(hsH + ((size_t)b * S_DIM + sc * 64 + p) * U_DIM) + hc;
  float a8[8] = {};
#pragma unroll 4
  for (int i = 0; i < 32; ++i) {
    float a = al[2 * i + p];
    half8 h = hp[(size_t)i * 256];
#pragma unroll
    for (int j = 0; j < 8; ++j) a8[j] = fmaf(a, (float)h[j], a8[j]);
  }
  if (p == 1) {
#pragma unroll
    for (int j = 0; j < 8; ++j) red[hc][j] = a8[j];
  }
  __syncthreads();
  if (p == 0) {
    float* cp = ctx + b * U_DIM + hc * 8;
#pragma unroll
    for (int j = 0; j < 8; ++j) atomicAdd(cp + j, a8[j] + red[hc][j]);
  }
}

// ---------------------------------------------------------------------------
extern "C" void kernel_launch(void* const* d_in, const int* in_sizes, int n_in,
                              void* d_out, int out_size, void* d_ws,
                              size_t ws_size, hipStream_t stream) {
  const float* s_prev = (const float*)d_in[0];
  const float* hs = (const float*)d_in[1];
  const float* Ww = (const float*)d_in[2];
  const float* Wb = (const float*)d_in[3];
  const float* Uw = (const float*)d_in[4];
  const float* Ub = (const float*)d_in[5];
  const float* Vw = (const float*)d_in[6];
  // d_in[7] = V_b: softmax-invariant constant shift, unused.

  float* out = (float*)d_out;
  float* ctx = out;
  float* alpha = out + B_DIM * U_DIM;

  char* ws = (char*)d_ws;
  _Float16* hsH = (_Float16*)ws;                                   // 128 MiB
  char* base = ws + (size_t)M_TOT * U_DIM * sizeof(_Float16);
  _Float16* UwT = (_Float16*)base;                                 // 2 MiB
  float* dec = (float*)(base + 2 * 1024 * 1024);                   // 128 KiB
  float* score = (float*)(base + 2 * 1024 * 1024 + 128 * 1024);    // 256 KiB

  hipMemsetAsync(dec, 0, (size_t)B_DIM * U_DIM * sizeof(float), stream);
  hipMemsetAsync(score, 0, (size_t)M_TOT * sizeof(float), stream);
  hipMemsetAsync(ctx, 0, (size_t)B_DIM * U_DIM * sizeof(float), stream);

  conv_transpose_uw<<<dim3(32, 32), 256, 0, stream>>>(Uw, UwT);
  decoder2<<<dim3(8, B_DIM), 256, 0, stream>>>(s_prev, Ww, Wb, dec);
  convert_hs<<<4096, 256, 0, stream>>>(hs, hsH, (size_t)M_TOT * U_DIM / 8);
  gemm_score_8p<<<1024, 512, 0, stream>>>(hsH, UwT, dec, Ub, Vw, score);
  softmax_kernel<<<B_DIM, 256, 0, stream>>>(score, alpha);
  context_h<<<dim3(32, B_DIM), 256, 0, stream>>>(hsH, alpha, ctx);
}